// Round 9
// baseline (919.379 us; speedup 1.0000x reference)
//
#include <hip/hip_runtime.h>
#include <hip/hip_bf16.h>

// Problem constants (match reference)
#define E_NUM 8
#define H_DIM 1024
#define F_DIM 4096
#define T_TOK 16384

#define NT 256
#define MT_MAX (T_TOK / 128 + E_NUM)    // 136 worst-case 128-row M tiles (fallback)
#define MT256 (T_TOK / 256 + E_NUM)     // 72 worst-case 256-row M tiles

typedef __attribute__((ext_vector_type(8))) short bf16x8;
typedef __attribute__((ext_vector_type(4))) float f32x4;

__device__ __forceinline__ short f2bf(float f) {
    unsigned u = __builtin_bit_cast(unsigned, f);
    u += 0x7FFFu + ((u >> 16) & 1u);
    return (short)(u >> 16);
}

__device__ __forceinline__ float exp2_fast(float a) {
#if __has_builtin(__builtin_amdgcn_exp2f)
    return __builtin_amdgcn_exp2f(a);
#else
    return exp2f(a);
#endif
}
__device__ __forceinline__ float rcp_fast(float a) {
#if __has_builtin(__builtin_amdgcn_rcpf)
    return __builtin_amdgcn_rcpf(a);
#else
    return 1.0f / a;
#endif
}

// tanh-form gelu: max |err| vs exact ~1e-3 (negligible vs bf16 noise)
__device__ __forceinline__ float fast_gelu(float x) {
    float x2 = x * x;
    float y = x * (0.7978845608f + 0.0356774081f * x2);
    float z = exp2_fast(y * 2.8853900817779268f);   // e^{2y}
    float r = rcp_fast(z + 1.0f);
    return x * (1.0f - r);
}

__device__ __forceinline__ void gload16(const void* g, void* l) {
    __builtin_amdgcn_global_load_lds(
        (const __attribute__((address_space(1))) void*)g,
        (__attribute__((address_space(3))) void*)l, 16, 0, 0);
}

template<int N>
__device__ __forceinline__ void vmwait() {
    if constexpr (N == 0) asm volatile("s_waitcnt vmcnt(0)" ::: "memory");
    else if constexpr (N == 4) asm volatile("s_waitcnt vmcnt(4)" ::: "memory");
    else if constexpr (N == 8) asm volatile("s_waitcnt vmcnt(8)" ::: "memory");
}

// raw barrier with compiler memory-ordering (no waitcnt insertion)
__device__ __forceinline__ void bar() {
    asm volatile("s_barrier" ::: "memory");
}

__device__ __forceinline__ void tile_map128(const int* __restrict__ cnt, int mt,
                                            int& row0, int& rend, int& e_out) {
    int acc = 0, off = 0;
    e_out = -1;
    for (int i = 0; i < E_NUM; ++i) {
        int c = cnt[i];
        int nti = (c + 127) >> 7;
        if (mt < acc + nti) {
            e_out = i; row0 = off + (mt - acc) * 128; rend = off + c; return;
        }
        acc += nti; off += c;
    }
}

__device__ __forceinline__ void tile_map256(const int* __restrict__ cnt, int mt,
                                            int& row0, int& rend, int& e_out) {
    int acc = 0, off = 0;
    e_out = -1;
    for (int i = 0; i < E_NUM; ++i) {
        int c = cnt[i];
        int nti = (c + 255) >> 8;
        if (mt < acc + nti) {
            e_out = i; row0 = off + (mt - acc) * 256; rend = off + c; return;
        }
        acc += nti; off += c;
    }
}

// ---------------------------------------------------------------------------
// Prep kernels
// ---------------------------------------------------------------------------
__global__ __launch_bounds__(NT)
void cvt_x_kernel(const float* __restrict__ in, short* __restrict__ out, int n8) {
    int i = blockIdx.x * blockDim.x + threadIdx.x;
    const int stride = gridDim.x * blockDim.x;
    for (; i < n8; i += stride) {
        f32x4 f0 = ((const f32x4*)in)[(size_t)i * 2];
        f32x4 f1 = ((const f32x4*)in)[(size_t)i * 2 + 1];
        bf16x8 v;
        v[0] = f2bf(f0[0]); v[1] = f2bf(f0[1]); v[2] = f2bf(f0[2]); v[3] = f2bf(f0[3]);
        v[4] = f2bf(f1[0]); v[5] = f2bf(f1[1]); v[6] = f2bf(f1[2]); v[7] = f2bf(f1[3]);
        ((bf16x8*)out)[i] = v;
    }
}

__global__ __launch_bounds__(NT)
void transpose_cvt(const float* __restrict__ in, short* __restrict__ out,
                   int R, int C) {
    __shared__ short tb[64][72];
    const int e = blockIdx.z;
    const float* ine = in + (size_t)e * R * C;
    short* oute = out + (size_t)e * R * C;
    const int c0 = blockIdx.x * 64, r0 = blockIdx.y * 64;
    const int t = threadIdx.x;
    const int rl = t >> 4, cl = (t & 15) * 4;
#pragma unroll
    for (int p = 0; p < 4; ++p) {
        int r = rl + p * 16;
        f32x4 f = *(const f32x4*)(ine + (size_t)(r0 + r) * C + c0 + cl);
#pragma unroll
        for (int j = 0; j < 4; ++j) tb[cl + j][r] = f2bf(f[j]);
    }
    __syncthreads();
    const int c2 = t >> 3, rc = (t & 7) * 8;
#pragma unroll
    for (int p = 0; p < 2; ++p) {
        int c = c2 + p * 32;
        bf16x8 v = *(const bf16x8*)&tb[c][rc];
        *(bf16x8*)(oute + (size_t)(c0 + c) * R + r0 + rc) = v;
    }
}

// ---------------------------------------------------------------------------
// 8-wave grouped GEMM, 256x256 tile, BK=32, 4-slot LDS ring, prefetch depth 3.
// (round-8 verified kernel, unchanged)
// ---------------------------------------------------------------------------
#define RING_RD_A(mh, SA)                                                     \
    _Pragma("unroll") for (int f = 0; f < 4; ++f) {                           \
        const int r_ = ((mh) * 4 + f) * 32 + wm * 16 + lr;                    \
        const int u_ = r_ * 4 + (lg ^ ((r_ >> 1) & 3));                       \
        areg[f] = ((const bf16x8*)(SA))[u_];                                  \
    }

#define RING_RD_B(SB)                                                         \
    _Pragma("unroll") for (int g = 0; g < 4; ++g) {                           \
        const int r_ = g * 64 + wn * 16 + lr;                                 \
        const int u_ = r_ * 4 + (lg ^ ((r_ >> 1) & 3));                       \
        breg[g] = ((const bf16x8*)(SB))[u_];                                  \
    }

#define RING_MM(mh)                                                           \
    _Pragma("unroll") for (int f = 0; f < 4; ++f)                             \
    _Pragma("unroll") for (int g = 0; g < 4; ++g)                             \
        acc[(mh) * 4 + f][g] = __builtin_amdgcn_mfma_f32_16x16x32_bf16(       \
            areg[f], breg[g], acc[(mh) * 4 + f][g], 0, 0, 0);

#define RING_KEEP(mh)                                                         \
    _Pragma("unroll") for (int f = 0; f < 4; ++f)                             \
    _Pragma("unroll") for (int g = 0; g < 4; ++g)                             \
        iacc[(mh) * 4 + f][g] += (int)(short)(areg[f][0] ^ breg[g][0]);

#define RING_STAGE_A(slot)                                                    \
    { short* base_ = lds + (slot) * SLOT;                                     \
      gload16(ag[0], base_ + d0); ag[0] += 32;                                \
      gload16(ag[1], base_ + d1); ag[1] += 32; }

#define RING_STAGE_B(slot)                                                    \
    { short* base_ = lds + (slot) * SLOT + 8192;                              \
      gload16(bg[0], base_ + d0); bg[0] += 32;                                \
      gload16(bg[1], base_ + d1); bg[1] += 32; }

template<bool GELU, int LDC, int NTX, int LDK>
__global__ __launch_bounds__(512, 2)
void gemm_ring(const short* __restrict__ A, const short* __restrict__ Bw,
               const int* __restrict__ cnt, void* __restrict__ Cout) {
    constexpr int SLOT = 16384;        // shorts per slot (A 8192 + B 8192)
    constexpr int KT = LDK / 32;
    static_assert(KT >= 4, "need at least 4 K-tiles");

    __shared__ __align__(16) short lds[4 * SLOT];   // 128 KiB

    constexpr int TOT = NTX * MT256;
    static_assert(TOT % 8 == 0, "grid must be divisible by 8 XCDs");
    constexpr int CPX = TOT / 8;
    const int lin = blockIdx.x;
    const int wg = (lin & 7) * CPX + (lin >> 3);
    const int mt = wg / NTX;
    const int nt = wg - mt * NTX;

    int row0, rend, e;
    tile_map256(cnt, mt, row0, rend, e);
    if (e < 0) return;
    const int n0 = nt * 256;
    const short* Be = Bw + (size_t)e * ((size_t)F_DIM * H_DIM);

    const int tid = threadIdx.x;
    const int lane = tid & 63;
    const int lr = lane & 15;
    const int lg = lane >> 4;
    const int w = tid >> 6;
    const int wm = w >> 2;
    const int wn = w & 3;

    const short* ag[2];
    const short* bg[2];
#pragma unroll
    for (int p = 0; p < 2; ++p) {
        int s = p * 512 + tid;
        int r = s >> 2;
        int kc = (s & 3) ^ ((r >> 1) & 3);
        int grow = row0 + r;
        if (grow >= T_TOK) grow = T_TOK - 1;
        ag[p] = A + (size_t)grow * LDK + kc * 8;
        bg[p] = Be + (size_t)(n0 + r) * LDK + kc * 8;
    }
    const int d0 = (0 * 512 + tid) * 8;
    const int d1 = (1 * 512 + tid) * 8;

    f32x4 acc[8][4];
#pragma unroll
    for (int i = 0; i < 8; ++i)
#pragma unroll
        for (int j = 0; j < 4; ++j) acc[i][j] = (f32x4){0.f, 0.f, 0.f, 0.f};
    bf16x8 areg[4];
    bf16x8 breg[4];

    RING_STAGE_A(0) RING_STAGE_B(0)
    RING_STAGE_A(1) RING_STAGE_B(1)
    RING_STAGE_A(2) RING_STAGE_B(2)

    int kt = 0;
    for (; kt < KT - 3; ++kt) {
        const short* Sa = lds + (kt & 3) * SLOT;
        const short* Sb = Sa + 8192;
        vmwait<8>();
        bar();
        RING_RD_B(Sb)
        RING_RD_A(0, Sa)
        RING_STAGE_A((kt + 3) & 3)
        __builtin_amdgcn_s_setprio(1);
        RING_MM(0)
        __builtin_amdgcn_s_setprio(0);
        RING_RD_A(1, Sa)
        RING_STAGE_B((kt + 3) & 3)
        __builtin_amdgcn_s_setprio(1);
        RING_MM(1)
        __builtin_amdgcn_s_setprio(0);
    }

    {
        const short* Sa = lds + (kt & 3) * SLOT;
        const short* Sb = Sa + 8192;
        vmwait<8>();
        bar();
        RING_RD_B(Sb) RING_RD_A(0, Sa) RING_MM(0)
        RING_RD_A(1, Sa) RING_MM(1)
        ++kt;
    }
    {
        const short* Sa = lds + (kt & 3) * SLOT;
        const short* Sb = Sa + 8192;
        vmwait<4>();
        bar();
        RING_RD_B(Sb) RING_RD_A(0, Sa) RING_MM(0)
        RING_RD_A(1, Sa) RING_MM(1)
        ++kt;
    }
    {
        const short* Sa = lds + (kt & 3) * SLOT;
        const short* Sb = Sa + 8192;
        vmwait<0>();
        bar();
        RING_RD_B(Sb) RING_RD_A(0, Sa) RING_MM(0)
        RING_RD_A(1, Sa) RING_MM(1)
    }

#pragma unroll
    for (int f = 0; f < 8; ++f) {
#pragma unroll
        for (int g = 0; g < 4; ++g) {
            const int gcol = n0 + g * 64 + wn * 16 + lr;
#pragma unroll
            for (int rr = 0; rr < 4; ++rr) {
                const int grow = row0 + f * 32 + wm * 16 + lg * 4 + rr;
                if (grow < rend) {
                    float v = acc[f][g][rr];
                    if constexpr (GELU) {
                        ((short*)Cout)[(size_t)grow * LDC + gcol] = f2bf(fast_gelu(v));
                    } else {
                        ((float*)Cout)[(size_t)grow * LDC + gcol] = v;
                    }
                }
            }
        }
    }
}

// ---------------------------------------------------------------------------
// ABLATION kernel (gemm1 geometry, NTX=16, LDK=1024), writes to scratch.
// MODE 1: staging path removed from loop (stage 3 tiles once; ds_read+MFMA).
// MODE 2: ds_read removed from loop (frags loaded once; stage+vmcnt+MFMA).
// MODE 3: MFMA removed (stage + ds_read kept; 1-op int keep-alive per pair).
// Identical grid/block/LDS/occupancy to the real gemm1 (regime fidelity).
// ---------------------------------------------------------------------------
template<int MODE>
__global__ __launch_bounds__(512, 2)
void gemm_abl(const short* __restrict__ A, const short* __restrict__ Bw,
              const int* __restrict__ cnt, short* __restrict__ Cout) {
    constexpr int NTX = 16;
    constexpr int LDK = H_DIM;
    constexpr int SLOT = 16384;
    constexpr int KT = LDK / 32;

    __shared__ __align__(16) short lds[4 * SLOT];

    constexpr int TOT = NTX * MT256;
    constexpr int CPX = TOT / 8;
    const int lin = blockIdx.x;
    const int wg = (lin & 7) * CPX + (lin >> 3);
    const int mt = wg / NTX;
    const int nt = wg - mt * NTX;

    int row0, rend, e;
    tile_map256(cnt, mt, row0, rend, e);
    if (e < 0) return;
    const int n0 = nt * 256;
    const short* Be = Bw + (size_t)e * ((size_t)F_DIM * H_DIM);

    const int tid = threadIdx.x;
    const int lane = tid & 63;
    const int lr = lane & 15;
    const int lg = lane >> 4;
    const int w = tid >> 6;
    const int wm = w >> 2;
    const int wn = w & 3;

    const short* ag[2];
    const short* bg[2];
#pragma unroll
    for (int p = 0; p < 2; ++p) {
        int s = p * 512 + tid;
        int r = s >> 2;
        int kc = (s & 3) ^ ((r >> 1) & 3);
        int grow = row0 + r;
        if (grow >= T_TOK) grow = T_TOK - 1;
        ag[p] = A + (size_t)grow * LDK + kc * 8;
        bg[p] = Be + (size_t)(n0 + r) * LDK + kc * 8;
    }
    const int d0 = (0 * 512 + tid) * 8;
    const int d1 = (1 * 512 + tid) * 8;

    f32x4 acc[8][4];
    int iacc[8][4];
#pragma unroll
    for (int i = 0; i < 8; ++i)
#pragma unroll
        for (int j = 0; j < 4; ++j) { acc[i][j] = (f32x4){0.f, 0.f, 0.f, 0.f}; iacc[i][j] = 0; }
    bf16x8 areg[4];
    bf16x8 breg[4];

    // prologue: stage 3 tiles
    RING_STAGE_A(0) RING_STAGE_B(0)
    RING_STAGE_A(1) RING_STAGE_B(1)
    RING_STAGE_A(2) RING_STAGE_B(2)

    if constexpr (MODE == 1) {
        // no staging in loop: drain prologue, then pure LDS+MFMA loop
        vmwait<0>();
        bar();
        for (int kt = 0; kt < KT; ++kt) {
            const short* Sa = lds + (kt & 3) * SLOT;
            const short* Sb = Sa + 8192;
            bar();
            RING_RD_B(Sb)
            RING_RD_A(0, Sa)
            __builtin_amdgcn_s_setprio(1);
            RING_MM(0)
            __builtin_amdgcn_s_setprio(0);
            RING_RD_A(1, Sa)
            __builtin_amdgcn_s_setprio(1);
            RING_MM(1)
            __builtin_amdgcn_s_setprio(0);
        }
    } else if constexpr (MODE == 2) {
        // no ds_read in loop: load frags once, keep staging+vmcnt+bar+MFMA
        vmwait<0>();
        bar();
        {
            const short* Sa = lds;
            const short* Sb = Sa + 8192;
            RING_RD_B(Sb)
            RING_RD_A(0, Sa)
        }
        for (int kt = 0; kt < KT - 3; ++kt) {
            vmwait<8>();
            bar();
            RING_STAGE_A((kt + 3) & 3)
            __builtin_amdgcn_s_setprio(1);
            RING_MM(0)
            __builtin_amdgcn_s_setprio(0);
            RING_STAGE_B((kt + 3) & 3)
            __builtin_amdgcn_s_setprio(1);
            RING_MM(1)
            __builtin_amdgcn_s_setprio(0);
        }
        vmwait<0>();
        bar();
        for (int kt = KT - 3; kt < KT; ++kt) {
            RING_MM(0)
            RING_MM(1)
        }
    } else {
        // MODE 3: staging + ds_read kept; MFMA -> int keep-alive
        for (int kt = 0; kt < KT - 3; ++kt) {
            const short* Sa = lds + (kt & 3) * SLOT;
            const short* Sb = Sa + 8192;
            vmwait<8>();
            bar();
            RING_RD_B(Sb)
            RING_RD_A(0, Sa)
            RING_STAGE_A((kt + 3) & 3)
            RING_KEEP(0)
            RING_RD_A(1, Sa)
            RING_STAGE_B((kt + 3) & 3)
            RING_KEEP(1)
        }
        for (int p = 0; p < 3; ++p) {
            const int kt = KT - 3 + p;
            const short* Sa = lds + (kt & 3) * SLOT;
            const short* Sb = Sa + 8192;
            if (p == 0) vmwait<8>(); else if (p == 1) vmwait<4>(); else vmwait<0>();
            bar();
            RING_RD_B(Sb) RING_RD_A(0, Sa) RING_KEEP(0)
            RING_RD_A(1, Sa) RING_KEEP(1)
        }
    }

    // epilogue to scratch (keeps everything live)
#pragma unroll
    for (int f = 0; f < 8; ++f) {
#pragma unroll
        for (int g = 0; g < 4; ++g) {
            const int gcol = n0 + g * 64 + wn * 16 + lr;
#pragma unroll
            for (int rr = 0; rr < 4; ++rr) {
                const int grow = row0 + f * 32 + wm * 16 + lg * 4 + rr;
                if (grow < rend) {
                    float v = acc[f][g][rr] + (float)iacc[f][g];
                    Cout[(size_t)grow * F_DIM + gcol] = f2bf(v);
                }
            }
        }
    }
}

// ---------------------------------------------------------------------------
// Round-1 fallback kernels (only used if ws too small for bf16 prep buffers)
// ---------------------------------------------------------------------------
__global__ __launch_bounds__(NT)
void gemm1_kernel(const float* __restrict__ X, const float* __restrict__ W1,
                  const int* __restrict__ cnt, short* __restrict__ act) {
    __shared__ short Alds[128 * 64];
    __shared__ short Blds[128 * 64];

    int row0, rend, e;
    tile_map128(cnt, blockIdx.y, row0, rend, e);
    if (e < 0) return;

    const int n0 = blockIdx.x * 128;
    const float* W = W1 + (size_t)e * H_DIM * F_DIM;

    const int tid = threadIdx.x;
    const int lane = tid & 63;
    const int w = tid >> 6;
    const int wr = (w >> 1) * 64;
    const int wc = (w & 1) * 64;
    const int lr = lane & 15;
    const int lg = lane >> 4;

    const int a_r0 = tid >> 3;
    const int a_kc = tid & 7;
    const int b_n = tid & 127;
    const int b_kg = (tid >> 7) * 8;

    f32x4 acc[4][4];
#pragma unroll
    for (int i = 0; i < 4; ++i)
#pragma unroll
        for (int j = 0; j < 4; ++j) acc[i][j] = (f32x4){0.f, 0.f, 0.f, 0.f};

    for (int kt = 0; kt < H_DIM / 64; ++kt) {
        const int k0 = kt * 64;
#pragma unroll
        for (int p = 0; p < 4; ++p) {
            int r = a_r0 + 32 * p;
            int grow = row0 + r;
            if (grow > T_TOK - 1) grow = T_TOK - 1;
            const float* src = X + (size_t)grow * H_DIM + k0 + a_kc * 8;
            f32x4 f0 = *(const f32x4*)src;
            f32x4 f1 = *(const f32x4*)(src + 4);
            bf16x8 v;
            v[0] = f2bf(f0[0]); v[1] = f2bf(f0[1]); v[2] = f2bf(f0[2]); v[3] = f2bf(f0[3]);
            v[4] = f2bf(f1[0]); v[5] = f2bf(f1[1]); v[6] = f2bf(f1[2]); v[7] = f2bf(f1[3]);
            ((bf16x8*)Alds)[(r * 8 + a_kc) ^ (r & 7)] = v;
        }
#pragma unroll
        for (int p = 0; p < 4; ++p) {
            int kb = p * 16 + b_kg;
            const float* src = W + (size_t)(k0 + kb) * F_DIM + n0 + b_n;
            bf16x8 v;
#pragma unroll
            for (int j = 0; j < 8; ++j) v[j] = f2bf(src[(size_t)j * F_DIM]);
            ((bf16x8*)Blds)[(b_n * 8 + (kb >> 3)) ^ (b_n & 7)] = v;
        }
        __syncthreads();
#pragma unroll
        for (int kk = 0; kk < 2; ++kk) {
            bf16x8 af[4], bfr[4];
#pragma unroll
            for (int fm = 0; fm < 4; ++fm) {
                int r = wr + fm * 16 + lr;
                af[fm] = ((bf16x8*)Alds)[(r * 8 + kk * 4 + lg) ^ (r & 7)];
            }
#pragma unroll
            for (int fn = 0; fn < 4; ++fn) {
                int n = wc + fn * 16 + lr;
                bfr[fn] = ((bf16x8*)Blds)[(n * 8 + kk * 4 + lg) ^ (n & 7)];
            }
#pragma unroll
            for (int fm = 0; fm < 4; ++fm)
#pragma unroll
                for (int fn = 0; fn < 4; ++fn)
                    acc[fm][fn] = __builtin_amdgcn_mfma_f32_16x16x32_bf16(
                        af[fm], bfr[fn], acc[fm][fn], 0, 0, 0);
        }
        __syncthreads();
    }

#pragma unroll
    for (int fm = 0; fm < 4; ++fm)
#pragma unroll
        for (int fn = 0; fn < 4; ++fn) {
            int gcol = n0 + wc + fn * 16 + lr;
#pragma unroll
            for (int rr = 0; rr < 4; ++rr) {
                int grow = row0 + wr + fm * 16 + lg * 4 + rr;
                if (grow < rend)
                    act[(size_t)grow * F_DIM + gcol] = f2bf(fast_gelu(acc[fm][fn][rr]));
            }
        }
}

__global__ __launch_bounds__(NT)
void gemm2_kernel(const short* __restrict__ ACT, const float* __restrict__ W2,
                  const int* __restrict__ cnt, float* __restrict__ out) {
    __shared__ short Alds[128 * 64];
    __shared__ short Blds[128 * 64];

    int row0, rend, e;
    tile_map128(cnt, blockIdx.y, row0, rend, e);
    if (e < 0) return;

    const int n0 = blockIdx.x * 128;
    const float* W = W2 + (size_t)e * F_DIM * H_DIM;

    const int tid = threadIdx.x;
    const int lane = tid & 63;
    const int w = tid >> 6;
    const int wr = (w >> 1) * 64;
    const int wc = (w & 1) * 64;
    const int lr = lane & 15;
    const int lg = lane >> 4;

    const int a_r0 = tid >> 3;
    const int a_kc = tid & 7;
    const int b_n = tid & 127;
    const int b_kg = (tid >> 7) * 8;

    f32x4 acc[4][4];
#pragma unroll
    for (int i = 0; i < 4; ++i)
#pragma unroll
        for (int j = 0; j < 4; ++j) acc[i][j] = (f32x4){0.f, 0.f, 0.f, 0.f};

    for (int kt = 0; kt < F_DIM / 64; ++kt) {
        const int k0 = kt * 64;
#pragma unroll
        for (int p = 0; p < 4; ++p) {
            int r = a_r0 + 32 * p;
            int grow = row0 + r;
            if (grow > T_TOK - 1) grow = T_TOK - 1;
            bf16x8 v = *(const bf16x8*)(ACT + (size_t)grow * F_DIM + k0 + a_kc * 8);
            ((bf16x8*)Alds)[(r * 8 + a_kc) ^ (r & 7)] = v;
        }
#pragma unroll
        for (int p = 0; p < 4; ++p) {
            int kb = p * 16 + b_kg;
            const float* src = W + (size_t)(k0 + kb) * H_DIM + n0 + b_n;
            bf16x8 v;
#pragma unroll
            for (int j = 0; j < 8; ++j) v[j] = f2bf(src[(size_t)j * H_DIM]);
            ((bf16x8*)Blds)[(b_n * 8 + (kb >> 3)) ^ (b_n & 7)] = v;
        }
        __syncthreads();
#pragma unroll
        for (int kk = 0; kk < 2; ++kk) {
            bf16x8 af[4], bfr[4];
#pragma unroll
            for (int fm = 0; fm < 4; ++fm) {
                int r = wr + fm * 16 + lr;
                af[fm] = ((bf16x8*)Alds)[(r * 8 + kk * 4 + lg) ^ (r & 7)];
            }
#pragma unroll
            for (int fn = 0; fn < 4; ++fn) {
                int n = wc + fn * 16 + lr;
                bfr[fn] = ((bf16x8*)Blds)[(n * 8 + kk * 4 + lg) ^ (n & 7)];
            }
#pragma unroll
            for (int fm = 0; fm < 4; ++fm)
#pragma unroll
                for (int fn = 0; fn < 4; ++fn)
                    acc[fm][fn] = __builtin_amdgcn_mfma_f32_16x16x32_bf16(
                        af[fm], bfr[fn], acc[fm][fn], 0, 0, 0);
        }
        __syncthreads();
    }

#pragma unroll
    for (int fm = 0; fm < 4; ++fm)
#pragma unroll
        for (int fn = 0; fn < 4; ++fn) {
            int gcol = n0 + wc + fn * 16 + lr;
#pragma unroll
            for (int rr = 0; rr < 4; ++rr) {
                int grow = row0 + wr + fm * 16 + lg * 4 + rr;
                if (grow < rend) out[(size_t)grow * H_DIM + gcol] = acc[fm][fn][rr];
            }
        }
}

extern "C" void kernel_launch(void* const* d_in, const int* in_sizes, int n_in,
                              void* d_out, int out_size, void* d_ws, size_t ws_size,
                              hipStream_t stream) {
    const float* x  = (const float*)d_in[0];
    const float* w1 = (const float*)d_in[1];
    const float* w2 = (const float*)d_in[2];
    const int* cnt  = (const int*)d_in[3];
    float* out = (float*)d_out;

    const size_t ACT_B = (size_t)T_TOK * F_DIM * 2;              // 128 MiB
    const size_t WT_B  = (size_t)E_NUM * F_DIM * H_DIM * 2;      //  64 MiB
    const size_t XB_B  = (size_t)T_TOK * H_DIM * 2;              //  32 MiB

    if (ws_size >= ACT_B + WT_B + XB_B) {
        short* act = (short*)d_ws;
        short* wt  = (short*)((char*)d_ws + ACT_B);
        short* xb  = (short*)((char*)d_ws + ACT_B + WT_B);

        cvt_x_kernel<<<2048, NT, 0, stream>>>(x, xb, T_TOK * H_DIM / 8);
        transpose_cvt<<<dim3(F_DIM / 64, H_DIM / 64, E_NUM), NT, 0, stream>>>(
            w1, wt, H_DIM, F_DIM);
        gemm_ring<true, F_DIM, 16, H_DIM>
            <<<16 * MT256, 512, 0, stream>>>(xb, wt, cnt, (void*)act);
        transpose_cvt<<<dim3(H_DIM / 64, F_DIM / 64, E_NUM), NT, 0, stream>>>(
            w2, wt, F_DIM, H_DIM);
        gemm_ring<false, H_DIM, 4, F_DIM>
            <<<4 * MT256, 512, 0, stream>>>(act, wt, cnt, (void*)out);

        // ---- ABLATION dispatches (after real pipeline; scratch = act region,
        // already consumed; output unaffected). Same geometry as real gemm1.
        gemm_abl<1><<<16 * MT256, 512, 0, stream>>>(xb, wt, cnt, act);
        gemm_abl<2><<<16 * MT256, 512, 0, stream>>>(xb, wt, cnt, act);
        gemm_abl<3><<<16 * MT256, 512, 0, stream>>>(xb, wt, cnt, act);
    } else if (ws_size >= ACT_B) {
        short* act = (short*)d_ws;
        gemm1_kernel<<<dim3(F_DIM / 128, MT_MAX), NT, 0, stream>>>(x, w1, cnt, act);
        gemm2_kernel<<<dim3(H_DIM / 128, MT_MAX), NT, 0, stream>>>(act, w2, cnt, out);
    }
}

// Round 10
// 529.391 us; speedup vs baseline: 1.7367x; 1.7367x over previous
//
#include <hip/hip_runtime.h>
#include <hip/hip_bf16.h>

// Problem constants (match reference)
#define E_NUM 8
#define H_DIM 1024
#define F_DIM 4096
#define T_TOK 16384

#define NT 256
#define MT_MAX (T_TOK / 128 + E_NUM)    // 136 worst-case 128-row M tiles (fallback)
#define MT256 (T_TOK / 256 + E_NUM)     // 72 worst-case 256-row M tiles

typedef __attribute__((ext_vector_type(8))) short bf16x8;
typedef __attribute__((ext_vector_type(4))) float f32x4;

__device__ __forceinline__ short f2bf(float f) {
    unsigned u = __builtin_bit_cast(unsigned, f);
    u += 0x7FFFu + ((u >> 16) & 1u);
    return (short)(u >> 16);
}

__device__ __forceinline__ float exp2_fast(float a) {
#if __has_builtin(__builtin_amdgcn_exp2f)
    return __builtin_amdgcn_exp2f(a);
#else
    return exp2f(a);
#endif
}
__device__ __forceinline__ float rcp_fast(float a) {
#if __has_builtin(__builtin_amdgcn_rcpf)
    return __builtin_amdgcn_rcpf(a);
#else
    return 1.0f / a;
#endif
}

// tanh-form gelu: max |err| vs exact ~1e-3 (negligible vs bf16 noise)
__device__ __forceinline__ float fast_gelu(float x) {
    float x2 = x * x;
    float y = x * (0.7978845608f + 0.0356774081f * x2);
    float z = exp2_fast(y * 2.8853900817779268f);   // e^{2y}
    float r = rcp_fast(z + 1.0f);
    return x * (1.0f - r);
}

__device__ __forceinline__ void gload16(const void* g, void* l) {
    __builtin_amdgcn_global_load_lds(
        (const __attribute__((address_space(1))) void*)g,
        (__attribute__((address_space(3))) void*)l, 16, 0, 0);
}

template<int N>
__device__ __forceinline__ void vmwait() {
    if constexpr (N == 0) asm volatile("s_waitcnt vmcnt(0)" ::: "memory");
    else if constexpr (N == 4) asm volatile("s_waitcnt vmcnt(4)" ::: "memory");
    else if constexpr (N == 8) asm volatile("s_waitcnt vmcnt(8)" ::: "memory");
}

__device__ __forceinline__ void lgkm0() {
    asm volatile("s_waitcnt lgkmcnt(0)" ::: "memory");
}

// raw barrier with compiler memory-ordering (no waitcnt insertion)
__device__ __forceinline__ void bar() {
    asm volatile("s_barrier" ::: "memory");
}

__device__ __forceinline__ void tile_map128(const int* __restrict__ cnt, int mt,
                                            int& row0, int& rend, int& e_out) {
    int acc = 0, off = 0;
    e_out = -1;
    for (int i = 0; i < E_NUM; ++i) {
        int c = cnt[i];
        int nti = (c + 127) >> 7;
        if (mt < acc + nti) {
            e_out = i; row0 = off + (mt - acc) * 128; rend = off + c; return;
        }
        acc += nti; off += c;
    }
}

__device__ __forceinline__ void tile_map256(const int* __restrict__ cnt, int mt,
                                            int& row0, int& rend, int& e_out) {
    int acc = 0, off = 0;
    e_out = -1;
    for (int i = 0; i < E_NUM; ++i) {
        int c = cnt[i];
        int nti = (c + 255) >> 8;
        if (mt < acc + nti) {
            e_out = i; row0 = off + (mt - acc) * 256; rend = off + c; return;
        }
        acc += nti; off += c;
    }
}

// ---------------------------------------------------------------------------
// Prep kernels
// ---------------------------------------------------------------------------
__global__ __launch_bounds__(NT)
void cvt_x_kernel(const float* __restrict__ in, short* __restrict__ out, int n8) {
    int i = blockIdx.x * blockDim.x + threadIdx.x;
    const int stride = gridDim.x * blockDim.x;
    for (; i < n8; i += stride) {
        f32x4 f0 = ((const f32x4*)in)[(size_t)i * 2];
        f32x4 f1 = ((const f32x4*)in)[(size_t)i * 2 + 1];
        bf16x8 v;
        v[0] = f2bf(f0[0]); v[1] = f2bf(f0[1]); v[2] = f2bf(f0[2]); v[3] = f2bf(f0[3]);
        v[4] = f2bf(f1[0]); v[5] = f2bf(f1[1]); v[6] = f2bf(f1[2]); v[7] = f2bf(f1[3]);
        ((bf16x8*)out)[i] = v;
    }
}

__global__ __launch_bounds__(NT)
void transpose_cvt(const float* __restrict__ in, short* __restrict__ out,
                   int R, int C) {
    __shared__ short tb[64][72];
    const int e = blockIdx.z;
    const float* ine = in + (size_t)e * R * C;
    short* oute = out + (size_t)e * R * C;
    const int c0 = blockIdx.x * 64, r0 = blockIdx.y * 64;
    const int t = threadIdx.x;
    const int rl = t >> 4, cl = (t & 15) * 4;
#pragma unroll
    for (int p = 0; p < 4; ++p) {
        int r = rl + p * 16;
        f32x4 f = *(const f32x4*)(ine + (size_t)(r0 + r) * C + c0 + cl);
#pragma unroll
        for (int j = 0; j < 4; ++j) tb[cl + j][r] = f2bf(f[j]);
    }
    __syncthreads();
    const int c2 = t >> 3, rc = (t & 7) * 8;
#pragma unroll
    for (int p = 0; p < 2; ++p) {
        int c = c2 + p * 32;
        bf16x8 v = *(const bf16x8*)&tb[c][rc];
        *(bf16x8*)(oute + (size_t)(c0 + c) * R + r0 + rc) = v;
    }
}

// ---------------------------------------------------------------------------
// 8-wave grouped GEMM, 256x256 tile, BK=32, 2-slot double buffer = 64 KiB LDS
// -> 2 blocks/CU. The two co-resident blocks have independent barriers, so
// one block's MFMA burst overlaps the other's LDS-read/staging convoy (m114
// wave-level overlap) without fragile intra-wave scheduling.
// Per K-tile kt (slot kt&1):
//   read B(4)+A0(4); MM(0); read A1(4); MM(1);      [all reads consumed]
//   lgkm0; bar;                                      [WAR-safe vs overwrite]
//   stage tile kt+2 -> slot kt&1 (4 gloads);
//   vmcnt(4) -> tile kt+1 landed; bar.
// Prologue stages t0,t1; peel last 2 tiles (vmcnt 0).
// Ledger: at stage-point outstanding = t_{kt+1}(4)+t_{kt+2}(4); vmcnt(4)
// retires t_{kt+1} exactly. Prefetch lead = 1 full K-tile body (>=1500 cyc)
// > 900-cyc HBM latency.
// Swizzle (BK=32): phys unit u = r*4 + (c ^ ((r>>1)&3)); staging source
// inverse-swizzled, global_load_lds dest linear (both-sides rule).
// ---------------------------------------------------------------------------
#define RING_RD_A(mh, SA)                                                     \
    _Pragma("unroll") for (int f = 0; f < 4; ++f) {                           \
        const int r_ = ((mh) * 4 + f) * 32 + wm * 16 + lr;                    \
        const int u_ = r_ * 4 + (lg ^ ((r_ >> 1) & 3));                       \
        areg[f] = ((const bf16x8*)(SA))[u_];                                  \
    }

#define RING_RD_B(SB)                                                         \
    _Pragma("unroll") for (int g = 0; g < 4; ++g) {                           \
        const int r_ = g * 64 + wn * 16 + lr;                                 \
        const int u_ = r_ * 4 + (lg ^ ((r_ >> 1) & 3));                       \
        breg[g] = ((const bf16x8*)(SB))[u_];                                  \
    }

#define RING_MM(mh)                                                           \
    _Pragma("unroll") for (int f = 0; f < 4; ++f)                             \
    _Pragma("unroll") for (int g = 0; g < 4; ++g)                             \
        acc[(mh) * 4 + f][g] = __builtin_amdgcn_mfma_f32_16x16x32_bf16(       \
            areg[f], breg[g], acc[(mh) * 4 + f][g], 0, 0, 0);

#define RING_STAGE_A(slot)                                                    \
    { short* base_ = lds + (slot) * SLOT;                                     \
      gload16(ag[0], base_ + d0); ag[0] += 32;                                \
      gload16(ag[1], base_ + d1); ag[1] += 32; }

#define RING_STAGE_B(slot)                                                    \
    { short* base_ = lds + (slot) * SLOT + 8192;                              \
      gload16(bg[0], base_ + d0); bg[0] += 32;                                \
      gload16(bg[1], base_ + d1); bg[1] += 32; }

template<bool GELU, int LDC, int NTX, int LDK>
__global__ __launch_bounds__(512, 2)
void gemm_ring(const short* __restrict__ A, const short* __restrict__ Bw,
               const int* __restrict__ cnt, void* __restrict__ Cout) {
    constexpr int SLOT = 16384;        // shorts per slot (A 8192 + B 8192)
    constexpr int KT = LDK / 32;
    static_assert(KT >= 4, "need at least 4 K-tiles");

    __shared__ __align__(16) short lds[2 * SLOT];   // 64 KiB -> 2 blocks/CU

    // bijective XCD swizzle
    constexpr int TOT = NTX * MT256;
    static_assert(TOT % 8 == 0, "grid must be divisible by 8 XCDs");
    constexpr int CPX = TOT / 8;
    const int lin = blockIdx.x;
    const int wg = (lin & 7) * CPX + (lin >> 3);
    const int mt = wg / NTX;
    const int nt = wg - mt * NTX;

    int row0, rend, e;
    tile_map256(cnt, mt, row0, rend, e);
    if (e < 0) return;
    const int n0 = nt * 256;
    const short* Be = Bw + (size_t)e * ((size_t)F_DIM * H_DIM);

    const int tid = threadIdx.x;
    const int lane = tid & 63;
    const int lr = lane & 15;
    const int lg = lane >> 4;
    const int w = tid >> 6;
    const int wm = w >> 2;         // 0..1
    const int wn = w & 3;          // 0..3

    // inverse-swizzled staging sources; 2 gload16 per operand per K-tile
    const short* ag[2];
    const short* bg[2];
#pragma unroll
    for (int p = 0; p < 2; ++p) {
        int s = p * 512 + tid;
        int r = s >> 2;
        int kc = (s & 3) ^ ((r >> 1) & 3);
        int grow = row0 + r;
        if (grow >= T_TOK) grow = T_TOK - 1;
        ag[p] = A + (size_t)grow * LDK + kc * 8;
        bg[p] = Be + (size_t)(n0 + r) * LDK + kc * 8;
    }
    const int d0 = (0 * 512 + tid) * 8;
    const int d1 = (1 * 512 + tid) * 8;

    f32x4 acc[8][4];
#pragma unroll
    for (int i = 0; i < 8; ++i)
#pragma unroll
        for (int j = 0; j < 4; ++j) acc[i][j] = (f32x4){0.f, 0.f, 0.f, 0.f};
    bf16x8 areg[4];
    bf16x8 breg[4];

    // ---- prologue: stage tiles 0 and 1 (8 loads: A0 B0 A1 B1)
    RING_STAGE_A(0) RING_STAGE_B(0)
    RING_STAGE_A(1) RING_STAGE_B(1)
    vmwait<4>();   // tile 0 landed; tile 1 in flight
    bar();

    int kt = 0;
    for (; kt < KT - 2; ++kt) {
        const short* Sa = lds + (kt & 1) * SLOT;
        const short* Sb = Sa + 8192;
        // compute tile kt (reads all consumed before the barrier)
        RING_RD_B(Sb)
        RING_RD_A(0, Sa)
        __builtin_amdgcn_s_setprio(1);
        RING_MM(0)
        __builtin_amdgcn_s_setprio(0);
        RING_RD_A(1, Sa)
        __builtin_amdgcn_s_setprio(1);
        RING_MM(1)
        __builtin_amdgcn_s_setprio(0);
        lgkm0();           // all slot reads complete (WAR safety)
        bar();             // every wave done reading slot kt&1
        // stage tile kt+2 into the slot just freed
        RING_STAGE_A(kt & 1)
        RING_STAGE_B(kt & 1)
        vmwait<4>();       // retires tile kt+1 (leaves kt+2's 4 in flight)
        bar();
    }

    // ---- peel kt = KT-2: compute; then drain tile KT-1
    {
        const short* Sa = lds + (kt & 1) * SLOT;
        const short* Sb = Sa + 8192;
        RING_RD_B(Sb) RING_RD_A(0, Sa) RING_MM(0)
        RING_RD_A(1, Sa) RING_MM(1)
        vmwait<0>();
        bar();
        ++kt;
    }
    // ---- peel kt = KT-1
    {
        const short* Sa = lds + (kt & 1) * SLOT;
        const short* Sb = Sa + 8192;
        RING_RD_B(Sb) RING_RD_A(0, Sa) RING_MM(0)
        RING_RD_A(1, Sa) RING_MM(1)
    }

    // ---- epilogue (same C-layout as verified rounds 4-8)
#pragma unroll
    for (int f = 0; f < 8; ++f) {
#pragma unroll
        for (int g = 0; g < 4; ++g) {
            const int gcol = n0 + g * 64 + wn * 16 + lr;
#pragma unroll
            for (int rr = 0; rr < 4; ++rr) {
                const int grow = row0 + f * 32 + wm * 16 + lg * 4 + rr;
                if (grow < rend) {
                    float v = acc[f][g][rr];
                    if constexpr (GELU) {
                        ((short*)Cout)[(size_t)grow * LDC + gcol] = f2bf(fast_gelu(v));
                    } else {
                        ((float*)Cout)[(size_t)grow * LDC + gcol] = v;
                    }
                }
            }
        }
    }
}

// ---------------------------------------------------------------------------
// Round-1 fallback kernels (only used if ws too small for bf16 prep buffers)
// ---------------------------------------------------------------------------
__global__ __launch_bounds__(NT)
void gemm1_kernel(const float* __restrict__ X, const float* __restrict__ W1,
                  const int* __restrict__ cnt, short* __restrict__ act) {
    __shared__ short Alds[128 * 64];
    __shared__ short Blds[128 * 64];

    int row0, rend, e;
    tile_map128(cnt, blockIdx.y, row0, rend, e);
    if (e < 0) return;

    const int n0 = blockIdx.x * 128;
    const float* W = W1 + (size_t)e * H_DIM * F_DIM;

    const int tid = threadIdx.x;
    const int lane = tid & 63;
    const int w = tid >> 6;
    const int wr = (w >> 1) * 64;
    const int wc = (w & 1) * 64;
    const int lr = lane & 15;
    const int lg = lane >> 4;

    const int a_r0 = tid >> 3;
    const int a_kc = tid & 7;
    const int b_n = tid & 127;
    const int b_kg = (tid >> 7) * 8;

    f32x4 acc[4][4];
#pragma unroll
    for (int i = 0; i < 4; ++i)
#pragma unroll
        for (int j = 0; j < 4; ++j) acc[i][j] = (f32x4){0.f, 0.f, 0.f, 0.f};

    for (int kt = 0; kt < H_DIM / 64; ++kt) {
        const int k0 = kt * 64;
#pragma unroll
        for (int p = 0; p < 4; ++p) {
            int r = a_r0 + 32 * p;
            int grow = row0 + r;
            if (grow > T_TOK - 1) grow = T_TOK - 1;
            const float* src = X + (size_t)grow * H_DIM + k0 + a_kc * 8;
            f32x4 f0 = *(const f32x4*)src;
            f32x4 f1 = *(const f32x4*)(src + 4);
            bf16x8 v;
            v[0] = f2bf(f0[0]); v[1] = f2bf(f0[1]); v[2] = f2bf(f0[2]); v[3] = f2bf(f0[3]);
            v[4] = f2bf(f1[0]); v[5] = f2bf(f1[1]); v[6] = f2bf(f1[2]); v[7] = f2bf(f1[3]);
            ((bf16x8*)Alds)[(r * 8 + a_kc) ^ (r & 7)] = v;
        }
#pragma unroll
        for (int p = 0; p < 4; ++p) {
            int kb = p * 16 + b_kg;
            const float* src = W + (size_t)(k0 + kb) * F_DIM + n0 + b_n;
            bf16x8 v;
#pragma unroll
            for (int j = 0; j < 8; ++j) v[j] = f2bf(src[(size_t)j * F_DIM]);
            ((bf16x8*)Blds)[(b_n * 8 + (kb >> 3)) ^ (b_n & 7)] = v;
        }
        __syncthreads();
#pragma unroll
        for (int kk = 0; kk < 2; ++kk) {
            bf16x8 af[4], bfr[4];
#pragma unroll
            for (int fm = 0; fm < 4; ++fm) {
                int r = wr + fm * 16 + lr;
                af[fm] = ((bf16x8*)Alds)[(r * 8 + kk * 4 + lg) ^ (r & 7)];
            }
#pragma unroll
            for (int fn = 0; fn < 4; ++fn) {
                int n = wc + fn * 16 + lr;
                bfr[fn] = ((bf16x8*)Blds)[(n * 8 + kk * 4 + lg) ^ (n & 7)];
            }
#pragma unroll
            for (int fm = 0; fm < 4; ++fm)
#pragma unroll
                for (int fn = 0; fn < 4; ++fn)
                    acc[fm][fn] = __builtin_amdgcn_mfma_f32_16x16x32_bf16(
                        af[fm], bfr[fn], acc[fm][fn], 0, 0, 0);
        }
        __syncthreads();
    }

#pragma unroll
    for (int fm = 0; fm < 4; ++fm)
#pragma unroll
        for (int fn = 0; fn < 4; ++fn) {
            int gcol = n0 + wc + fn * 16 + lr;
#pragma unroll
            for (int rr = 0; rr < 4; ++rr) {
                int grow = row0 + wr + fm * 16 + lg * 4 + rr;
                if (grow < rend)
                    act[(size_t)grow * F_DIM + gcol] = f2bf(fast_gelu(acc[fm][fn][rr]));
            }
        }
}

__global__ __launch_bounds__(NT)
void gemm2_kernel(const short* __restrict__ ACT, const float* __restrict__ W2,
                  const int* __restrict__ cnt, float* __restrict__ out) {
    __shared__ short Alds[128 * 64];
    __shared__ short Blds[128 * 64];

    int row0, rend, e;
    tile_map128(cnt, blockIdx.y, row0, rend, e);
    if (e < 0) return;

    const int n0 = blockIdx.x * 128;
    const float* W = W2 + (size_t)e * F_DIM * H_DIM;

    const int tid = threadIdx.x;
    const int lane = tid & 63;
    const int w = tid >> 6;
    const int wr = (w >> 1) * 64;
    const int wc = (w & 1) * 64;
    const int lr = lane & 15;
    const int lg = lane >> 4;

    const int a_r0 = tid >> 3;
    const int a_kc = tid & 7;
    const int b_n = tid & 127;
    const int b_kg = (tid >> 7) * 8;

    f32x4 acc[4][4];
#pragma unroll
    for (int i = 0; i < 4; ++i)
#pragma unroll
        for (int j = 0; j < 4; ++j) acc[i][j] = (f32x4){0.f, 0.f, 0.f, 0.f};

    for (int kt = 0; kt < F_DIM / 64; ++kt) {
        const int k0 = kt * 64;
#pragma unroll
        for (int p = 0; p < 4; ++p) {
            int r = a_r0 + 32 * p;
            int grow = row0 + r;
            if (grow > T_TOK - 1) grow = T_TOK - 1;
            bf16x8 v = *(const bf16x8*)(ACT + (size_t)grow * F_DIM + k0 + a_kc * 8);
            ((bf16x8*)Alds)[(r * 8 + a_kc) ^ (r & 7)] = v;
        }
#pragma unroll
        for (int p = 0; p < 4; ++p) {
            int kb = p * 16 + b_kg;
            const float* src = W + (size_t)(k0 + kb) * H_DIM + n0 + b_n;
            bf16x8 v;
#pragma unroll
            for (int j = 0; j < 8; ++j) v[j] = f2bf(src[(size_t)j * H_DIM]);
            ((bf16x8*)Blds)[(b_n * 8 + (kb >> 3)) ^ (b_n & 7)] = v;
        }
        __syncthreads();
#pragma unroll
        for (int kk = 0; kk < 2; ++kk) {
            bf16x8 af[4], bfr[4];
#pragma unroll
            for (int fm = 0; fm < 4; ++fm) {
                int r = wr + fm * 16 + lr;
                af[fm] = ((bf16x8*)Alds)[(r * 8 + kk * 4 + lg) ^ (r & 7)];
            }
#pragma unroll
            for (int fn = 0; fn < 4; ++fn) {
                int n = wc + fn * 16 + lr;
                bfr[fn] = ((bf16x8*)Blds)[(n * 8 + kk * 4 + lg) ^ (n & 7)];
            }
#pragma unroll
            for (int fm = 0; fm < 4; ++fm)
#pragma unroll
                for (int fn = 0; fn < 4; ++fn)
                    acc[fm][fn] = __builtin_amdgcn_mfma_f32_16x16x32_bf16(
                        af[fm], bfr[fn], acc[fm][fn], 0, 0, 0);
        }
        __syncthreads();
    }

#pragma unroll
    for (int fm = 0; fm < 4; ++fm)
#pragma unroll
        for (int fn = 0; fn < 4; ++fn) {
            int gcol = n0 + wc + fn * 16 + lr;
#pragma unroll
            for (int rr = 0; rr < 4; ++rr) {
                int grow = row0 + wr + fm * 16 + lg * 4 + rr;
                if (grow < rend) out[(size_t)grow * H_DIM + gcol] = acc[fm][fn][rr];
            }
        }
}

extern "C" void kernel_launch(void* const* d_in, const int* in_sizes, int n_in,
                              void* d_out, int out_size, void* d_ws, size_t ws_size,
                              hipStream_t stream) {
    const float* x  = (const float*)d_in[0];
    const float* w1 = (const float*)d_in[1];
    const float* w2 = (const float*)d_in[2];
    const int* cnt  = (const int*)d_in[3];
    float* out = (float*)d_out;

    const size_t ACT_B = (size_t)T_TOK * F_DIM * 2;              // 128 MiB
    const size_t WT_B  = (size_t)E_NUM * F_DIM * H_DIM * 2;      //  64 MiB
    const size_t XB_B  = (size_t)T_TOK * H_DIM * 2;              //  32 MiB

    if (ws_size >= ACT_B + WT_B + XB_B) {
        short* act = (short*)d_ws;
        short* wt  = (short*)((char*)d_ws + ACT_B);
        short* xb  = (short*)((char*)d_ws + ACT_B + WT_B);

        cvt_x_kernel<<<2048, NT, 0, stream>>>(x, xb, T_TOK * H_DIM / 8);
        transpose_cvt<<<dim3(F_DIM / 64, H_DIM / 64, E_NUM), NT, 0, stream>>>(
            w1, wt, H_DIM, F_DIM);
        gemm_ring<true, F_DIM, 16, H_DIM>
            <<<16 * MT256, 512, 0, stream>>>(xb, wt, cnt, (void*)act);
        transpose_cvt<<<dim3(H_DIM / 64, F_DIM / 64, E_NUM), NT, 0, stream>>>(
            w2, wt, F_DIM, H_DIM);
        gemm_ring<false, H_DIM, 4, F_DIM>
            <<<4 * MT256, 512, 0, stream>>>(act, wt, cnt, (void*)out);
    } else if (ws_size >= ACT_B) {
        short* act = (short*)d_ws;
        gemm1_kernel<<<dim3(F_DIM / 128, MT_MAX), NT, 0, stream>>>(x, w1, cnt, act);
        gemm2_kernel<<<dim3(H_DIM / 128, MT_MAX), NT, 0, stream>>>(act, w2, cnt, out);
    }
}

// Round 11
// 496.478 us; speedup vs baseline: 1.8518x; 1.0663x over previous
//
#include <hip/hip_runtime.h>
#include <hip/hip_bf16.h>

// Problem constants (match reference)
#define E_NUM 8
#define H_DIM 1024
#define F_DIM 4096
#define T_TOK 16384

#define NT 256
#define MT_MAX (T_TOK / 128 + E_NUM)    // 136 worst-case 128-row M tiles

typedef __attribute__((ext_vector_type(8))) short bf16x8;
typedef __attribute__((ext_vector_type(4))) float f32x4;

__device__ __forceinline__ short f2bf(float f) {
    unsigned u = __builtin_bit_cast(unsigned, f);
    u += 0x7FFFu + ((u >> 16) & 1u);
    return (short)(u >> 16);
}

__device__ __forceinline__ float exp2_fast(float a) {
#if __has_builtin(__builtin_amdgcn_exp2f)
    return __builtin_amdgcn_exp2f(a);
#else
    return exp2f(a);
#endif
}
__device__ __forceinline__ float rcp_fast(float a) {
#if __has_builtin(__builtin_amdgcn_rcpf)
    return __builtin_amdgcn_rcpf(a);
#else
    return 1.0f / a;
#endif
}

// tanh-form gelu: max |err| vs exact ~1e-3 (negligible vs bf16 noise)
__device__ __forceinline__ float fast_gelu(float x) {
    float x2 = x * x;
    float y = x * (0.7978845608f + 0.0356774081f * x2);
    float z = exp2_fast(y * 2.8853900817779268f);   // e^{2y}
    float r = rcp_fast(z + 1.0f);
    return x * (1.0f - r);
}

__device__ __forceinline__ void gload16(const void* g, void* l) {
    __builtin_amdgcn_global_load_lds(
        (const __attribute__((address_space(1))) void*)g,
        (__attribute__((address_space(3))) void*)l, 16, 0, 0);
}

template<int N>
__device__ __forceinline__ void vmwait() {
    if constexpr (N == 0) asm volatile("s_waitcnt vmcnt(0)" ::: "memory");
    else if constexpr (N == 4) asm volatile("s_waitcnt vmcnt(4)" ::: "memory");
    else if constexpr (N == 8) asm volatile("s_waitcnt vmcnt(8)" ::: "memory");
}

// raw barrier with compiler memory-ordering (no waitcnt insertion)
__device__ __forceinline__ void bar() {
    asm volatile("s_barrier" ::: "memory");
}

__device__ __forceinline__ void tile_map128(const int* __restrict__ cnt, int mt,
                                            int& row0, int& rend, int& e_out) {
    int acc = 0, off = 0;
    e_out = -1;
    for (int i = 0; i < E_NUM; ++i) {
        int c = cnt[i];
        int nti = (c + 127) >> 7;
        if (mt < acc + nti) {
            e_out = i; row0 = off + (mt - acc) * 128; rend = off + c; return;
        }
        acc += nti; off += c;
    }
}

// ---------------------------------------------------------------------------
// Prep kernels
// ---------------------------------------------------------------------------
__global__ __launch_bounds__(NT)
void cvt_x_kernel(const float* __restrict__ in, short* __restrict__ out, int n8) {
    int i = blockIdx.x * blockDim.x + threadIdx.x;
    const int stride = gridDim.x * blockDim.x;
    for (; i < n8; i += stride) {
        f32x4 f0 = ((const f32x4*)in)[(size_t)i * 2];
        f32x4 f1 = ((const f32x4*)in)[(size_t)i * 2 + 1];
        bf16x8 v;
        v[0] = f2bf(f0[0]); v[1] = f2bf(f0[1]); v[2] = f2bf(f0[2]); v[3] = f2bf(f0[3]);
        v[4] = f2bf(f1[0]); v[5] = f2bf(f1[1]); v[6] = f2bf(f1[2]); v[7] = f2bf(f1[3]);
        ((bf16x8*)out)[i] = v;
    }
}

__global__ __launch_bounds__(NT)
void transpose_cvt(const float* __restrict__ in, short* __restrict__ out,
                   int R, int C) {
    __shared__ short tb[64][72];
    const int e = blockIdx.z;
    const float* ine = in + (size_t)e * R * C;
    short* oute = out + (size_t)e * R * C;
    const int c0 = blockIdx.x * 64, r0 = blockIdx.y * 64;
    const int t = threadIdx.x;
    const int rl = t >> 4, cl = (t & 15) * 4;
#pragma unroll
    for (int p = 0; p < 4; ++p) {
        int r = rl + p * 16;
        f32x4 f = *(const f32x4*)(ine + (size_t)(r0 + r) * C + c0 + cl);
#pragma unroll
        for (int j = 0; j < 4; ++j) tb[cl + j][r] = f2bf(f[j]);
    }
    __syncthreads();
    const int c2 = t >> 3, rc = (t & 7) * 8;
#pragma unroll
    for (int p = 0; p < 2; ++p) {
        int c = c2 + p * 32;
        bf16x8 v = *(const bf16x8*)&tb[c][rc];
        *(bf16x8*)(oute + (size_t)(c0 + c) * R + r0 + rc) = v;
    }
}

// ---------------------------------------------------------------------------
// 4-wave grouped GEMM, 128x128 tile, BK=32, 3-slot LDS ring = 48 KiB
// -> 3 blocks/CU (launch_bounds(256,3)). Three co-resident blocks have
// INDEPENDENT barrier domains: while one block's waves are in their LDS-read
// or stage-wait burst, another block's waves feed the MFMA pipe (m114
// overlap). This attacks the measured zero-overlap convoy (r9 ablation:
// stage ~63us + LDS ~63us + MFMA ~82us summing to 208us serial).
// Per K-tile kt (read slot kt%3, stage slot (kt+2)%3):
//   vmcnt(4)  -> retires tile kt's 4 loads exactly (kt+1's 4 remain)
//   s_barrier -> all waves see slot kt%3 complete
//   RD_B(4 b128) RD_A(4 b128); STAGE_A(kt+2); 8 MFMA; STAGE_B(kt+2); 8 MFMA
// WAR safety: slot (kt+2)%3 was last read at tile kt-1; those ds_reads were
// consumed (lgkm-enforced) before their wave reached this tile's barrier.
// Peel last 2 tiles: waits 4 / 0. Swizzle: unit u = r*4 + (lg ^ ((r>>1)&3))
// (2-way bank aliasing = free, 0 conflicts verified r8); staging source
// inverse-swizzled, global_load_lds dest linear (both-sides rule).
// ---------------------------------------------------------------------------
#define R3_RD_A(SA)                                                           \
    _Pragma("unroll") for (int fm = 0; fm < 4; ++fm) {                        \
        const int r_ = wr + fm * 16 + lr;                                     \
        const int u_ = r_ * 4 + (lg ^ ((r_ >> 1) & 3));                       \
        af[fm] = ((const bf16x8*)(SA))[u_];                                   \
    }

#define R3_RD_B(SB)                                                           \
    _Pragma("unroll") for (int fn = 0; fn < 4; ++fn) {                        \
        const int n_ = wc + fn * 16 + lr;                                     \
        const int u_ = n_ * 4 + (lg ^ ((n_ >> 1) & 3));                       \
        bf[fn] = ((const bf16x8*)(SB))[u_];                                   \
    }

#define R3_MM_H(h)                                                            \
    _Pragma("unroll") for (int fm = 0; fm < 4; ++fm)                          \
    _Pragma("unroll") for (int fn = (h) * 2; fn < (h) * 2 + 2; ++fn)          \
        acc[fm][fn] = __builtin_amdgcn_mfma_f32_16x16x32_bf16(                \
            af[fm], bf[fn], acc[fm][fn], 0, 0, 0);

#define R3_ST_A(slot)                                                         \
    { short* b_ = lds + (slot) * SLOT;                                        \
      gload16(ag[0], b_ + tid * 8);         ag[0] += 32;                      \
      gload16(ag[1], b_ + (256 + tid) * 8); ag[1] += 32; }

#define R3_ST_B(slot)                                                         \
    { short* b_ = lds + (slot) * SLOT + 4096;                                 \
      gload16(bg[0], b_ + tid * 8);         bg[0] += 32;                      \
      gload16(bg[1], b_ + (256 + tid) * 8); bg[1] += 32; }

template<bool GELU, int LDC, int NTX, int LDK>
__global__ __launch_bounds__(256, 3)
void gemm_r3(const short* __restrict__ A, const short* __restrict__ Bw,
             const int* __restrict__ cnt, void* __restrict__ Cout) {
    constexpr int SLOT = 8192;         // shorts per slot: A 4096 + B 4096 (16KB)
    constexpr int KT = LDK / 32;
    static_assert(KT >= 3, "need at least 3 K-tiles");

    __shared__ __align__(16) short lds[3 * SLOT];   // 48 KiB -> 3 blocks/CU

    // bijective XCD swizzle
    constexpr int TOT = NTX * MT_MAX;
    static_assert(TOT % 8 == 0, "grid must be divisible by 8 XCDs");
    constexpr int CPX = TOT / 8;
    const int lin = blockIdx.x;
    const int wg = (lin & 7) * CPX + (lin >> 3);
    const int mt = wg / NTX;
    const int nt = wg - mt * NTX;

    int row0, rend, e;
    tile_map128(cnt, mt, row0, rend, e);
    if (e < 0) return;
    const int n0 = nt * 128;
    const short* Be = Bw + (size_t)e * ((size_t)F_DIM * H_DIM);

    const int tid = threadIdx.x;
    const int lane = tid & 63;
    const int lr = lane & 15;
    const int lg = lane >> 4;
    const int w = tid >> 6;
    const int wr = (w >> 1) * 64;
    const int wc = (w & 1) * 64;

    // inverse-swizzled staging sources; 2 gload16 per operand per K-tile
    const short* ag[2];
    const short* bg[2];
#pragma unroll
    for (int p = 0; p < 2; ++p) {
        int s = p * 256 + tid;
        int r = s >> 2;
        int kc = (s & 3) ^ ((r >> 1) & 3);
        int grow = row0 + r;
        if (grow >= T_TOK) grow = T_TOK - 1;
        ag[p] = A + (size_t)grow * LDK + kc * 8;
        bg[p] = Be + (size_t)(n0 + r) * LDK + kc * 8;
    }

    f32x4 acc[4][4];
#pragma unroll
    for (int i = 0; i < 4; ++i)
#pragma unroll
        for (int j = 0; j < 4; ++j) acc[i][j] = (f32x4){0.f, 0.f, 0.f, 0.f};
    bf16x8 af[4];
    bf16x8 bf[4];

    // ---- prologue: stage tiles 0 (slot 0) and 1 (slot 1)
    R3_ST_A(0) R3_ST_B(0)
    R3_ST_A(1) R3_ST_B(1)
    vmwait<4>();   // tile 0 landed; tile 1 in flight
    bar();

    int s_rd = 0;        // slot holding tile kt
    int s_st = 2;        // slot to stage tile kt+2 into
    for (int kt = 0; kt < KT - 2; ++kt) {
        const short* Sa = lds + s_rd * SLOT;
        const short* Sb = Sa + 4096;
        R3_RD_B(Sb)
        R3_RD_A(Sa)
        R3_ST_A(s_st)
        __builtin_amdgcn_s_setprio(1);
        R3_MM_H(0)
        __builtin_amdgcn_s_setprio(0);
        R3_ST_B(s_st)
        __builtin_amdgcn_s_setprio(1);
        R3_MM_H(1)
        __builtin_amdgcn_s_setprio(0);
        s_rd = (s_rd == 2) ? 0 : s_rd + 1;
        s_st = (s_st == 2) ? 0 : s_st + 1;
        vmwait<4>();   // retires tile kt+1's loads (kt+2's 4 remain)
        bar();
    }

    // ---- peel kt = KT-2 (tile already landed via loop-exit wait)
    {
        const short* Sa = lds + s_rd * SLOT;
        const short* Sb = Sa + 4096;
        R3_RD_B(Sb) R3_RD_A(Sa)
        R3_MM_H(0) R3_MM_H(1)
        s_rd = (s_rd == 2) ? 0 : s_rd + 1;
        vmwait<0>();   // drain tile KT-1
        bar();
    }
    // ---- peel kt = KT-1
    {
        const short* Sa = lds + s_rd * SLOT;
        const short* Sb = Sa + 4096;
        R3_RD_B(Sb) R3_RD_A(Sa)
        R3_MM_H(0) R3_MM_H(1)
    }

    // ---- epilogue (round-2 verified mapping)
#pragma unroll
    for (int fm = 0; fm < 4; ++fm) {
#pragma unroll
        for (int fn = 0; fn < 4; ++fn) {
            const int gcol = n0 + wc + fn * 16 + lr;
#pragma unroll
            for (int rr = 0; rr < 4; ++rr) {
                const int grow = row0 + wr + fm * 16 + lg * 4 + rr;
                if (grow < rend) {
                    float v = acc[fm][fn][rr];
                    if constexpr (GELU) {
                        ((short*)Cout)[(size_t)grow * LDC + gcol] = f2bf(fast_gelu(v));
                    } else {
                        ((float*)Cout)[(size_t)grow * LDC + gcol] = v;
                    }
                }
            }
        }
    }
}

// ---------------------------------------------------------------------------
// Round-1 fallback kernels (only used if ws too small for bf16 prep buffers)
// ---------------------------------------------------------------------------
__global__ __launch_bounds__(NT)
void gemm1_kernel(const float* __restrict__ X, const float* __restrict__ W1,
                  const int* __restrict__ cnt, short* __restrict__ act) {
    __shared__ short Alds[128 * 64];
    __shared__ short Blds[128 * 64];

    int row0, rend, e;
    tile_map128(cnt, blockIdx.y, row0, rend, e);
    if (e < 0) return;

    const int n0 = blockIdx.x * 128;
    const float* W = W1 + (size_t)e * H_DIM * F_DIM;

    const int tid = threadIdx.x;
    const int lane = tid & 63;
    const int w = tid >> 6;
    const int wr = (w >> 1) * 64;
    const int wc = (w & 1) * 64;
    const int lr = lane & 15;
    const int lg = lane >> 4;

    const int a_r0 = tid >> 3;
    const int a_kc = tid & 7;
    const int b_n = tid & 127;
    const int b_kg = (tid >> 7) * 8;

    f32x4 acc[4][4];
#pragma unroll
    for (int i = 0; i < 4; ++i)
#pragma unroll
        for (int j = 0; j < 4; ++j) acc[i][j] = (f32x4){0.f, 0.f, 0.f, 0.f};

    for (int kt = 0; kt < H_DIM / 64; ++kt) {
        const int k0 = kt * 64;
#pragma unroll
        for (int p = 0; p < 4; ++p) {
            int r = a_r0 + 32 * p;
            int grow = row0 + r;
            if (grow > T_TOK - 1) grow = T_TOK - 1;
            const float* src = X + (size_t)grow * H_DIM + k0 + a_kc * 8;
            f32x4 f0 = *(const f32x4*)src;
            f32x4 f1 = *(const f32x4*)(src + 4);
            bf16x8 v;
            v[0] = f2bf(f0[0]); v[1] = f2bf(f0[1]); v[2] = f2bf(f0[2]); v[3] = f2bf(f0[3]);
            v[4] = f2bf(f1[0]); v[5] = f2bf(f1[1]); v[6] = f2bf(f1[2]); v[7] = f2bf(f1[3]);
            ((bf16x8*)Alds)[(r * 8 + a_kc) ^ (r & 7)] = v;
        }
#pragma unroll
        for (int p = 0; p < 4; ++p) {
            int kb = p * 16 + b_kg;
            const float* src = W + (size_t)(k0 + kb) * F_DIM + n0 + b_n;
            bf16x8 v;
#pragma unroll
            for (int j = 0; j < 8; ++j) v[j] = f2bf(src[(size_t)j * F_DIM]);
            ((bf16x8*)Blds)[(b_n * 8 + (kb >> 3)) ^ (b_n & 7)] = v;
        }
        __syncthreads();
#pragma unroll
        for (int kk = 0; kk < 2; ++kk) {
            bf16x8 af2[4], bf2[4];
#pragma unroll
            for (int fm = 0; fm < 4; ++fm) {
                int r = wr + fm * 16 + lr;
                af2[fm] = ((bf16x8*)Alds)[(r * 8 + kk * 4 + lg) ^ (r & 7)];
            }
#pragma unroll
            for (int fn = 0; fn < 4; ++fn) {
                int n = wc + fn * 16 + lr;
                bf2[fn] = ((bf16x8*)Blds)[(n * 8 + kk * 4 + lg) ^ (n & 7)];
            }
#pragma unroll
            for (int fm = 0; fm < 4; ++fm)
#pragma unroll
                for (int fn = 0; fn < 4; ++fn)
                    acc[fm][fn] = __builtin_amdgcn_mfma_f32_16x16x32_bf16(
                        af2[fm], bf2[fn], acc[fm][fn], 0, 0, 0);
        }
        __syncthreads();
    }

#pragma unroll
    for (int fm = 0; fm < 4; ++fm)
#pragma unroll
        for (int fn = 0; fn < 4; ++fn) {
            int gcol = n0 + wc + fn * 16 + lr;
#pragma unroll
            for (int rr = 0; rr < 4; ++rr) {
                int grow = row0 + wr + fm * 16 + lg * 4 + rr;
                if (grow < rend)
                    act[(size_t)grow * F_DIM + gcol] = f2bf(fast_gelu(acc[fm][fn][rr]));
            }
        }
}

__global__ __launch_bounds__(NT)
void gemm2_kernel(const short* __restrict__ ACT, const float* __restrict__ W2,
                  const int* __restrict__ cnt, float* __restrict__ out) {
    __shared__ short Alds[128 * 64];
    __shared__ short Blds[128 * 64];

    int row0, rend, e;
    tile_map128(cnt, blockIdx.y, row0, rend, e);
    if (e < 0) return;

    const int n0 = blockIdx.x * 128;
    const float* W = W2 + (size_t)e * F_DIM * H_DIM;

    const int tid = threadIdx.x;
    const int lane = tid & 63;
    const int w = tid >> 6;
    const int wr = (w >> 1) * 64;
    const int wc = (w & 1) * 64;
    const int lr = lane & 15;
    const int lg = lane >> 4;

    const int a_r0 = tid >> 3;
    const int a_kc = tid & 7;
    const int b_n = tid & 127;
    const int b_kg = (tid >> 7) * 8;

    f32x4 acc[4][4];
#pragma unroll
    for (int i = 0; i < 4; ++i)
#pragma unroll
        for (int j = 0; j < 4; ++j) acc[i][j] = (f32x4){0.f, 0.f, 0.f, 0.f};

    for (int kt = 0; kt < F_DIM / 64; ++kt) {
        const int k0 = kt * 64;
#pragma unroll
        for (int p = 0; p < 4; ++p) {
            int r = a_r0 + 32 * p;
            int grow = row0 + r;
            if (grow > T_TOK - 1) grow = T_TOK - 1;
            bf16x8 v = *(const bf16x8*)(ACT + (size_t)grow * F_DIM + k0 + a_kc * 8);
            ((bf16x8*)Alds)[(r * 8 + a_kc) ^ (r & 7)] = v;
        }
#pragma unroll
        for (int p = 0; p < 4; ++p) {
            int kb = p * 16 + b_kg;
            const float* src = W + (size_t)(k0 + kb) * H_DIM + n0 + b_n;
            bf16x8 v;
#pragma unroll
            for (int j = 0; j < 8; ++j) v[j] = f2bf(src[(size_t)j * H_DIM]);
            ((bf16x8*)Blds)[(b_n * 8 + (kb >> 3)) ^ (b_n & 7)] = v;
        }
        __syncthreads();
#pragma unroll
        for (int kk = 0; kk < 2; ++kk) {
            bf16x8 af2[4], bf2[4];
#pragma unroll
            for (int fm = 0; fm < 4; ++fm) {
                int r = wr + fm * 16 + lr;
                af2[fm] = ((bf16x8*)Alds)[(r * 8 + kk * 4 + lg) ^ (r & 7)];
            }
#pragma unroll
            for (int fn = 0; fn < 4; ++fn) {
                int n = wc + fn * 16 + lr;
                bf2[fn] = ((bf16x8*)Blds)[(n * 8 + kk * 4 + lg) ^ (n & 7)];
            }
#pragma unroll
            for (int fm = 0; fm < 4; ++fm)
#pragma unroll
                for (int fn = 0; fn < 4; ++fn)
                    acc[fm][fn] = __builtin_amdgcn_mfma_f32_16x16x32_bf16(
                        af2[fm], bf2[fn], acc[fm][fn], 0, 0, 0);
        }
        __syncthreads();
    }

#pragma unroll
    for (int fm = 0; fm < 4; ++fm)
#pragma unroll
        for (int fn = 0; fn < 4; ++fn) {
            int gcol = n0 + wc + fn * 16 + lr;
#pragma unroll
            for (int rr = 0; rr < 4; ++rr) {
                int grow = row0 + wr + fm * 16 + lg * 4 + rr;
                if (grow < rend) out[(size_t)grow * H_DIM + gcol] = acc[fm][fn][rr];
            }
        }
}

extern "C" void kernel_launch(void* const* d_in, const int* in_sizes, int n_in,
                              void* d_out, int out_size, void* d_ws, size_t ws_size,
                              hipStream_t stream) {
    const float* x  = (const float*)d_in[0];
    const float* w1 = (const float*)d_in[1];
    const float* w2 = (const float*)d_in[2];
    const int* cnt  = (const int*)d_in[3];
    float* out = (float*)d_out;

    const size_t ACT_B = (size_t)T_TOK * F_DIM * 2;              // 128 MiB
    const size_t WT_B  = (size_t)E_NUM * F_DIM * H_DIM * 2;      //  64 MiB
    const size_t XB_B  = (size_t)T_TOK * H_DIM * 2;              //  32 MiB

    if (ws_size >= ACT_B + WT_B + XB_B) {
        short* act = (short*)d_ws;
        short* wt  = (short*)((char*)d_ws + ACT_B);
        short* xb  = (short*)((char*)d_ws + ACT_B + WT_B);

        cvt_x_kernel<<<2048, NT, 0, stream>>>(x, xb, T_TOK * H_DIM / 8);
        transpose_cvt<<<dim3(F_DIM / 64, H_DIM / 64, E_NUM), NT, 0, stream>>>(
            w1, wt, H_DIM, F_DIM);
        gemm_r3<true, F_DIM, 32, H_DIM>
            <<<32 * MT_MAX, 256, 0, stream>>>(xb, wt, cnt, (void*)act);
        transpose_cvt<<<dim3(H_DIM / 64, F_DIM / 64, E_NUM), NT, 0, stream>>>(
            w2, wt, F_DIM, H_DIM);
        gemm_r3<false, H_DIM, 8, F_DIM>
            <<<8 * MT_MAX, 256, 0, stream>>>(act, wt, cnt, (void*)out);
    } else if (ws_size >= ACT_B) {
        short* act = (short*)d_ws;
        gemm1_kernel<<<dim3(F_DIM / 128, MT_MAX), NT, 0, stream>>>(x, w1, cnt, act);
        gemm2_kernel<<<dim3(H_DIM / 128, MT_MAX), NT, 0, stream>>>(act, w2, cnt, out);
    }
}

// Round 12
// 491.938 us; speedup vs baseline: 1.8689x; 1.0092x over previous
//
#include <hip/hip_runtime.h>
#include <hip/hip_bf16.h>

// Problem constants (match reference)
#define E_NUM 8
#define H_DIM 1024
#define F_DIM 4096
#define T_TOK 16384

#define NT 256
#define MT_MAX (T_TOK / 128 + E_NUM)    // 136 worst-case 128-row M tiles (fallback)
#define MT256 (T_TOK / 256 + E_NUM)     // 72 worst-case 256-row M tiles

typedef __attribute__((ext_vector_type(8))) short bf16x8;
typedef __attribute__((ext_vector_type(4))) float f32x4;

__device__ __forceinline__ short f2bf(float f) {
    unsigned u = __builtin_bit_cast(unsigned, f);
    u += 0x7FFFu + ((u >> 16) & 1u);
    return (short)(u >> 16);
}

__device__ __forceinline__ float exp2_fast(float a) {
#if __has_builtin(__builtin_amdgcn_exp2f)
    return __builtin_amdgcn_exp2f(a);
#else
    return exp2f(a);
#endif
}
__device__ __forceinline__ float rcp_fast(float a) {
#if __has_builtin(__builtin_amdgcn_rcpf)
    return __builtin_amdgcn_rcpf(a);
#else
    return 1.0f / a;
#endif
}

// tanh-form gelu: max |err| vs exact ~1e-3 (negligible vs bf16 noise)
__device__ __forceinline__ float fast_gelu(float x) {
    float x2 = x * x;
    float y = x * (0.7978845608f + 0.0356774081f * x2);
    float z = exp2_fast(y * 2.8853900817779268f);   // e^{2y}
    float r = rcp_fast(z + 1.0f);
    return x * (1.0f - r);
}

__device__ __forceinline__ void gload16(const void* g, void* l) {
    __builtin_amdgcn_global_load_lds(
        (const __attribute__((address_space(1))) void*)g,
        (__attribute__((address_space(3))) void*)l, 16, 0, 0);
}

template<int N>
__device__ __forceinline__ void vmwait() {
    if constexpr (N == 0) asm volatile("s_waitcnt vmcnt(0)" ::: "memory");
    else if constexpr (N == 2) asm volatile("s_waitcnt vmcnt(2)" ::: "memory");
    else if constexpr (N == 4) asm volatile("s_waitcnt vmcnt(4)" ::: "memory");
}

__device__ __forceinline__ void lgkm0() {
    asm volatile("s_waitcnt lgkmcnt(0)" ::: "memory");
}

// raw barrier with compiler memory-ordering (no waitcnt insertion)
__device__ __forceinline__ void bar() {
    asm volatile("s_barrier" ::: "memory");
}

__device__ __forceinline__ void tile_map128(const int* __restrict__ cnt, int mt,
                                            int& row0, int& rend, int& e_out) {
    int acc = 0, off = 0;
    e_out = -1;
    for (int i = 0; i < E_NUM; ++i) {
        int c = cnt[i];
        int nti = (c + 127) >> 7;
        if (mt < acc + nti) {
            e_out = i; row0 = off + (mt - acc) * 128; rend = off + c; return;
        }
        acc += nti; off += c;
    }
}

__device__ __forceinline__ void tile_map256(const int* __restrict__ cnt, int mt,
                                            int& row0, int& rend, int& e_out) {
    int acc = 0, off = 0;
    e_out = -1;
    for (int i = 0; i < E_NUM; ++i) {
        int c = cnt[i];
        int nti = (c + 255) >> 8;
        if (mt < acc + nti) {
            e_out = i; row0 = off + (mt - acc) * 256; rend = off + c; return;
        }
        acc += nti; off += c;
    }
}

// ---------------------------------------------------------------------------
// Prep kernels
// ---------------------------------------------------------------------------
__global__ __launch_bounds__(NT)
void cvt_x_kernel(const float* __restrict__ in, short* __restrict__ out, int n8) {
    int i = blockIdx.x * blockDim.x + threadIdx.x;
    const int stride = gridDim.x * blockDim.x;
    for (; i < n8; i += stride) {
        f32x4 f0 = ((const f32x4*)in)[(size_t)i * 2];
        f32x4 f1 = ((const f32x4*)in)[(size_t)i * 2 + 1];
        bf16x8 v;
        v[0] = f2bf(f0[0]); v[1] = f2bf(f0[1]); v[2] = f2bf(f0[2]); v[3] = f2bf(f0[3]);
        v[4] = f2bf(f1[0]); v[5] = f2bf(f1[1]); v[6] = f2bf(f1[2]); v[7] = f2bf(f1[3]);
        ((bf16x8*)out)[i] = v;
    }
}

__global__ __launch_bounds__(NT)
void transpose_cvt(const float* __restrict__ in, short* __restrict__ out,
                   int R, int C) {
    __shared__ short tb[64][72];
    const int e = blockIdx.z;
    const float* ine = in + (size_t)e * R * C;
    short* oute = out + (size_t)e * R * C;
    const int c0 = blockIdx.x * 64, r0 = blockIdx.y * 64;
    const int t = threadIdx.x;
    const int rl = t >> 4, cl = (t & 15) * 4;
#pragma unroll
    for (int p = 0; p < 4; ++p) {
        int r = rl + p * 16;
        f32x4 f = *(const f32x4*)(ine + (size_t)(r0 + r) * C + c0 + cl);
#pragma unroll
        for (int j = 0; j < 4; ++j) tb[cl + j][r] = f2bf(f[j]);
    }
    __syncthreads();
    const int c2 = t >> 3, rc = (t & 7) * 8;
#pragma unroll
    for (int p = 0; p < 2; ++p) {
        int c = c2 + p * 32;
        bf16x8 v = *(const bf16x8*)&tb[c][rc];
        *(bf16x8*)(oute + (size_t)(c0 + c) * R + r0 + rc) = v;
    }
}

// ---------------------------------------------------------------------------
// 8-wave grouped GEMM, 256x256 tile, BK=64, m201-faithful 4-phase/K-tile with
// BARRIER PAIR per phase: {reads; stage; bar; lgkm0; prio1 16xMFMA prio0;
// [vmcnt] bar}. Waits attached to phase-CLOSE (protect next phase's ds_reads).
// Issue order per tile (1-tile lead): P1->a0', P2->b0', P3->b1', P4->a1'.
// Steady ledger (2 loads/half): P1-close Q=[b1,a1,a0']6 -> vmcnt(4) retires b1
// (P2 reads B1); P2-close Q=[a1,a0',b0']6 -> vmcnt(4) retires a1 (P3 reads A1);
// P3-close none; P4-close Q=[a0',b0',b1',a1']8 -> vmcnt(4) retires a0',b0'
// (next P1 reads A0,B0). All waits' targets issued >=2 phases (~1300cyc) back.
// WAR: stage at tile t targets buffer last read at t-1, separated by >=3 bars.
// Peel (no stage): P1-close vmcnt(2), P2-close vmcnt(0).
// LDS XOR swizzle unit(r,kc)=(r*8+kc)^(r&7); inverse-swizzled global source,
// linear global_load_lds dest (both-sides rule). XCD swizzle = round-6 map.
// ---------------------------------------------------------------------------
#define G8P_READ_A(mh)                                                        \
    _Pragma("unroll") for (int f = 0; f < 4; ++f) {                           \
        const int r_ = ((mh) * 4 + f) * 32 + wm * 16 + lr;                    \
        _Pragma("unroll") for (int kk = 0; kk < 2; ++kk) {                    \
            const int u_ = (r_ * 8 + kk * 4 + lg) ^ (r_ & 7);                 \
            areg[f][kk] = ((const bf16x8*)Ac)[u_];                            \
        }                                                                     \
    }

#define G8P_READ_B(nh)                                                        \
    _Pragma("unroll") for (int g = 0; g < 2; ++g) {                           \
        const int r_ = ((nh) * 2 + g) * 64 + wn * 16 + lr;                    \
        _Pragma("unroll") for (int kk = 0; kk < 2; ++kk) {                    \
            const int u_ = (r_ * 8 + kk * 4 + lg) ^ (r_ & 7);                 \
            breg[nh][g][kk] = ((const bf16x8*)Bc)[u_];                        \
        }                                                                     \
    }

#define G8P_QUAD(mh, nh)                                                      \
    _Pragma("unroll") for (int f = 0; f < 4; ++f)                             \
    _Pragma("unroll") for (int g = 0; g < 2; ++g)                             \
    _Pragma("unroll") for (int kk = 0; kk < 2; ++kk)                          \
        acc[(mh) * 4 + f][(nh) * 2 + g] =                                     \
            __builtin_amdgcn_mfma_f32_16x16x32_bf16(                          \
                areg[f][kk], breg[nh][g][kk],                                 \
                acc[(mh) * 4 + f][(nh) * 2 + g], 0, 0, 0);

#define G8P_MFMA_PHASE(mh, nh)                                                \
    bar();                                                                    \
    lgkm0();                                                                  \
    __builtin_amdgcn_s_setprio(1);                                            \
    G8P_QUAD(mh, nh)                                                          \
    __builtin_amdgcn_s_setprio(0);

template<bool GELU, int LDC, int NTX, int KTOT>
__global__ __launch_bounds__(512, 2)
void gemm8p(const short* __restrict__ A, const short* __restrict__ Bw,
            const int* __restrict__ cnt, void* __restrict__ Cout) {
    // fixed geometry: BM=BN=256, WM=2, WN=4 -> MF=8, NF=4, 16 MFMA/phase
    constexpr int A_SH = 16384;            // shorts per A tile (256*64)
    constexpr int SEG = 32768;             // shorts per LDS buffer (A+B)
    constexpr int KT = KTOT / 64;
    static_assert(KT >= 2, "need at least 2 K-tiles");

    __shared__ __align__(16) short lds[2 * SEG];

    // bijective XCD swizzle (round-6 mapping: mt-major)
    constexpr int TOT = NTX * MT256;
    static_assert(TOT % 8 == 0, "grid must be divisible by 8 XCDs");
    constexpr int CPX = TOT / 8;
    const int lin = blockIdx.x;
    const int wg = (lin & 7) * CPX + (lin >> 3);
    const int mt = wg / NTX;
    const int nt = wg - mt * NTX;

    int row0, rend, e;
    tile_map256(cnt, mt, row0, rend, e);
    if (e < 0) return;
    const int n0 = nt * 256;
    const short* Be = Bw + (size_t)e * ((size_t)F_DIM * H_DIM);

    const int tid = threadIdx.x;
    const int lane = tid & 63;
    const int lr = lane & 15;
    const int lg = lane >> 4;
    const int w = tid >> 6;
    const int wm = w >> 2;         // 0..1
    const int wn = w & 3;          // 0..3

    // inverse-swizzled staging sources (half h = pointers 2h, 2h+1)
    const short* ag[4];
    const short* bg[4];
#pragma unroll
    for (int p = 0; p < 4; ++p) {
        int s = p * 512 + tid;
        int r = s >> 3;
        int kc = (s & 7) ^ (r & 7);
        int grow = row0 + r;
        if (grow >= T_TOK) grow = T_TOK - 1;
        ag[p] = A + (size_t)grow * KTOT + kc * 8;
        bg[p] = Be + (size_t)(n0 + r) * KTOT + kc * 8;
    }

    f32x4 acc[8][4];
#pragma unroll
    for (int i = 0; i < 8; ++i)
#pragma unroll
        for (int j = 0; j < 4; ++j) acc[i][j] = (f32x4){0.f, 0.f, 0.f, 0.f};
    bf16x8 areg[4][2];
    bf16x8 breg[2][2][2];

    // ---- prologue: stage tile 0, issue order [a0, b0, b1, a1]
    {
        short* An = lds;
        short* Bn = lds + A_SH;
        gload16(ag[0], An + (0 * 512 + tid) * 8); ag[0] += 64;
        gload16(ag[1], An + (1 * 512 + tid) * 8); ag[1] += 64;
        gload16(bg[0], Bn + (0 * 512 + tid) * 8); bg[0] += 64;
        gload16(bg[1], Bn + (1 * 512 + tid) * 8); bg[1] += 64;
        gload16(bg[2], Bn + (2 * 512 + tid) * 8); bg[2] += 64;
        gload16(bg[3], Bn + (3 * 512 + tid) * 8); bg[3] += 64;
        gload16(ag[2], An + (2 * 512 + tid) * 8); ag[2] += 64;
        gload16(ag[3], An + (3 * 512 + tid) * 8); ag[3] += 64;
    }
    vmwait<4>();   // a0_0, b0_0 landed; b1_0, a1_0 in flight
    bar();

    int cur = 0;
    // Main loop (always prefetches tile kt+1) — steady-state ledger above.
    for (int kt = 0; kt < KT - 1; ++kt) {
        const short* Ac = lds + cur * SEG;
        const short* Bc = Ac + A_SH;
        short* An = lds + (cur ^ 1) * SEG;
        short* Bn = An + A_SH;

        // ---- P1: read A0+B0; stage next a0
        G8P_READ_A(0)
        G8P_READ_B(0)
        gload16(ag[0], An + (0 * 512 + tid) * 8); ag[0] += 64;
        gload16(ag[1], An + (1 * 512 + tid) * 8); ag[1] += 64;
        G8P_MFMA_PHASE(0, 0)
        vmwait<4>();       // retires this tile's b1 (P2 reads B1)
        bar();

        // ---- P2: read B1; stage next b0
        G8P_READ_B(1)
        gload16(bg[0], Bn + (0 * 512 + tid) * 8); bg[0] += 64;
        gload16(bg[1], Bn + (1 * 512 + tid) * 8); bg[1] += 64;
        G8P_MFMA_PHASE(0, 1)
        vmwait<4>();       // retires this tile's a1 (P3 reads A1)
        bar();

        // ---- P3: read A1; stage next b1
        G8P_READ_A(1)
        gload16(bg[2], Bn + (2 * 512 + tid) * 8); bg[2] += 64;
        gload16(bg[3], Bn + (3 * 512 + tid) * 8); bg[3] += 64;
        G8P_MFMA_PHASE(1, 1)
        bar();

        // ---- P4: stage next a1 (frags A1,B0 reused from regs)
        gload16(ag[2], An + (2 * 512 + tid) * 8); ag[2] += 64;
        gload16(ag[3], An + (3 * 512 + tid) * 8); ag[3] += 64;
        G8P_MFMA_PHASE(1, 0)
        vmwait<4>();       // retires next tile's a0,b0 (next P1 reads them)
        bar();
        cur ^= 1;
    }

    // ---- peeled final K-tile (no staging): entry Q = [b1(2), a1(2)]
    {
        const short* Ac = lds + cur * SEG;
        const short* Bc = Ac + A_SH;
        G8P_READ_A(0)
        G8P_READ_B(0)
        G8P_MFMA_PHASE(0, 0)
        vmwait<2>();       // retire b1
        bar();
        G8P_READ_B(1)
        G8P_MFMA_PHASE(0, 1)
        vmwait<0>();       // retire a1
        bar();
        G8P_READ_A(1)
        G8P_MFMA_PHASE(1, 1)
        bar();
        G8P_MFMA_PHASE(1, 0)
    }

    // ---- epilogue (verified mapping, rounds 4-8)
#pragma unroll
    for (int f = 0; f < 8; ++f) {
#pragma unroll
        for (int g = 0; g < 4; ++g) {
            const int gcol = n0 + g * 64 + wn * 16 + lr;
#pragma unroll
            for (int rr = 0; rr < 4; ++rr) {
                const int grow = row0 + f * 32 + wm * 16 + lg * 4 + rr;
                if (grow < rend) {
                    float v = acc[f][g][rr];
                    if constexpr (GELU) {
                        ((short*)Cout)[(size_t)grow * LDC + gcol] = f2bf(fast_gelu(v));
                    } else {
                        ((float*)Cout)[(size_t)grow * LDC + gcol] = v;
                    }
                }
            }
        }
    }
}

// ---------------------------------------------------------------------------
// Round-1 fallback kernels (only used if ws too small for bf16 prep buffers)
// ---------------------------------------------------------------------------
__global__ __launch_bounds__(NT)
void gemm1_kernel(const float* __restrict__ X, const float* __restrict__ W1,
                  const int* __restrict__ cnt, short* __restrict__ act) {
    __shared__ short Alds[128 * 64];
    __shared__ short Blds[128 * 64];

    int row0, rend, e;
    tile_map128(cnt, blockIdx.y, row0, rend, e);
    if (e < 0) return;

    const int n0 = blockIdx.x * 128;
    const float* W = W1 + (size_t)e * H_DIM * F_DIM;

    const int tid = threadIdx.x;
    const int lane = tid & 63;
    const int w = tid >> 6;
    const int wr = (w >> 1) * 64;
    const int wc = (w & 1) * 64;
    const int lr = lane & 15;
    const int lg = lane >> 4;

    const int a_r0 = tid >> 3;
    const int a_kc = tid & 7;
    const int b_n = tid & 127;
    const int b_kg = (tid >> 7) * 8;

    f32x4 acc[4][4];
#pragma unroll
    for (int i = 0; i < 4; ++i)
#pragma unroll
        for (int j = 0; j < 4; ++j) acc[i][j] = (f32x4){0.f, 0.f, 0.f, 0.f};

    for (int kt = 0; kt < H_DIM / 64; ++kt) {
        const int k0 = kt * 64;
#pragma unroll
        for (int p = 0; p < 4; ++p) {
            int r = a_r0 + 32 * p;
            int grow = row0 + r;
            if (grow > T_TOK - 1) grow = T_TOK - 1;
            const float* src = X + (size_t)grow * H_DIM + k0 + a_kc * 8;
            f32x4 f0 = *(const f32x4*)src;
            f32x4 f1 = *(const f32x4*)(src + 4);
            bf16x8 v;
            v[0] = f2bf(f0[0]); v[1] = f2bf(f0[1]); v[2] = f2bf(f0[2]); v[3] = f2bf(f0[3]);
            v[4] = f2bf(f1[0]); v[5] = f2bf(f1[1]); v[6] = f2bf(f1[2]); v[7] = f2bf(f1[3]);
            ((bf16x8*)Alds)[(r * 8 + a_kc) ^ (r & 7)] = v;
        }
#pragma unroll
        for (int p = 0; p < 4; ++p) {
            int kb = p * 16 + b_kg;
            const float* src = W + (size_t)(k0 + kb) * F_DIM + n0 + b_n;
            bf16x8 v;
#pragma unroll
            for (int j = 0; j < 8; ++j) v[j] = f2bf(src[(size_t)j * F_DIM]);
            ((bf16x8*)Blds)[(b_n * 8 + (kb >> 3)) ^ (b_n & 7)] = v;
        }
        __syncthreads();
#pragma unroll
        for (int kk = 0; kk < 2; ++kk) {
            bf16x8 af2[4], bf2[4];
#pragma unroll
            for (int fm = 0; fm < 4; ++fm) {
                int r = wr + fm * 16 + lr;
                af2[fm] = ((bf16x8*)Alds)[(r * 8 + kk * 4 + lg) ^ (r & 7)];
            }
#pragma unroll
            for (int fn = 0; fn < 4; ++fn) {
                int n = wc + fn * 16 + lr;
                bf2[fn] = ((bf16x8*)Blds)[(n * 8 + kk * 4 + lg) ^ (n & 7)];
            }
#pragma unroll
            for (int fm = 0; fm < 4; ++fm)
#pragma unroll
                for (int fn = 0; fn < 4; ++fn)
                    acc[fm][fn] = __builtin_amdgcn_mfma_f32_16x16x32_bf16(
                        af2[fm], bf2[fn], acc[fm][fn], 0, 0, 0);
        }
        __syncthreads();
    }

#pragma unroll
    for (int fm = 0; fm < 4; ++fm)
#pragma unroll
        for (int fn = 0; fn < 4; ++fn) {
            int gcol = n0 + wc + fn * 16 + lr;
#pragma unroll
            for (int rr = 0; rr < 4; ++rr) {
                int grow = row0 + wr + fm * 16 + lg * 4 + rr;
                if (grow < rend)
                    act[(size_t)grow * F_DIM + gcol] = f2bf(fast_gelu(acc[fm][fn][rr]));
            }
        }
}

__global__ __launch_bounds__(NT)
void gemm2_kernel(const short* __restrict__ ACT, const float* __restrict__ W2,
                  const int* __restrict__ cnt, float* __restrict__ out) {
    __shared__ short Alds[128 * 64];
    __shared__ short Blds[128 * 64];

    int row0, rend, e;
    tile_map128(cnt, blockIdx.y, row0, rend, e);
    if (e < 0) return;

    const int n0 = blockIdx.x * 128;
    const float* W = W2 + (size_t)e * F_DIM * H_DIM;

    const int tid = threadIdx.x;
    const int lane = tid & 63;
    const int w = tid >> 6;
    const int wr = (w >> 1) * 64;
    const int wc = (w & 1) * 64;
    const int lr = lane & 15;
    const int lg = lane >> 4;

    const int a_r0 = tid >> 3;
    const int a_kc = tid & 7;
    const int b_n = tid & 127;
    const int b_kg = (tid >> 7) * 8;

    f32x4 acc[4][4];
#pragma unroll
    for (int i = 0; i < 4; ++i)
#pragma unroll
        for (int j = 0; j < 4; ++j) acc[i][j] = (f32x4){0.f, 0.f, 0.f, 0.f};

    for (int kt = 0; kt < F_DIM / 64; ++kt) {
        const int k0 = kt * 64;
#pragma unroll
        for (int p = 0; p < 4; ++p) {
            int r = a_r0 + 32 * p;
            int grow = row0 + r;
            if (grow > T_TOK - 1) grow = T_TOK - 1;
            bf16x8 v = *(const bf16x8*)(ACT + (size_t)grow * F_DIM + k0 + a_kc * 8);
            ((bf16x8*)Alds)[(r * 8 + a_kc) ^ (r & 7)] = v;
        }
#pragma unroll
        for (int p = 0; p < 4; ++p) {
            int kb = p * 16 + b_kg;
            const float* src = W + (size_t)(k0 + kb) * H_DIM + n0 + b_n;
            bf16x8 v;
#pragma unroll
            for (int j = 0; j < 8; ++j) v[j] = f2bf(src[(size_t)j * H_DIM]);
            ((bf16x8*)Blds)[(b_n * 8 + (kb >> 3)) ^ (b_n & 7)] = v;
        }
        __syncthreads();
#pragma unroll
        for (int kk = 0; kk < 2; ++kk) {
            bf16x8 af2[4], bf2[4];
#pragma unroll
            for (int fm = 0; fm < 4; ++fm) {
                int r = wr + fm * 16 + lr;
                af2[fm] = ((bf16x8*)Alds)[(r * 8 + kk * 4 + lg) ^ (r & 7)];
            }
#pragma unroll
            for (int fn = 0; fn < 4; ++fn) {
                int n = wc + fn * 16 + lr;
                bf2[fn] = ((bf16x8*)Blds)[(n * 8 + kk * 4 + lg) ^ (n & 7)];
            }
#pragma unroll
            for (int fm = 0; fm < 4; ++fm)
#pragma unroll
                for (int fn = 0; fn < 4; ++fn)
                    acc[fm][fn] = __builtin_amdgcn_mfma_f32_16x16x32_bf16(
                        af2[fm], bf2[fn], acc[fm][fn], 0, 0, 0);
        }
        __syncthreads();
    }

#pragma unroll
    for (int fm = 0; fm < 4; ++fm)
#pragma unroll
        for (int fn = 0; fn < 4; ++fn) {
            int gcol = n0 + wc + fn * 16 + lr;
#pragma unroll
            for (int rr = 0; rr < 4; ++rr) {
                int grow = row0 + wr + fm * 16 + lg * 4 + rr;
                if (grow < rend) out[(size_t)grow * H_DIM + gcol] = acc[fm][fn][rr];
            }
        }
}

extern "C" void kernel_launch(void* const* d_in, const int* in_sizes, int n_in,
                              void* d_out, int out_size, void* d_ws, size_t ws_size,
                              hipStream_t stream) {
    const float* x  = (const float*)d_in[0];
    const float* w1 = (const float*)d_in[1];
    const float* w2 = (const float*)d_in[2];
    const int* cnt  = (const int*)d_in[3];
    float* out = (float*)d_out;

    const size_t ACT_B = (size_t)T_TOK * F_DIM * 2;              // 128 MiB
    const size_t WT_B  = (size_t)E_NUM * F_DIM * H_DIM * 2;      //  64 MiB
    const size_t XB_B  = (size_t)T_TOK * H_DIM * 2;              //  32 MiB

    if (ws_size >= ACT_B + WT_B + XB_B) {
        short* act = (short*)d_ws;
        short* wt  = (short*)((char*)d_ws + ACT_B);
        short* xb  = (short*)((char*)d_ws + ACT_B + WT_B);

        cvt_x_kernel<<<2048, NT, 0, stream>>>(x, xb, T_TOK * H_DIM / 8);
        transpose_cvt<<<dim3(F_DIM / 64, H_DIM / 64, E_NUM), NT, 0, stream>>>(
            w1, wt, H_DIM, F_DIM);
        gemm8p<true, F_DIM, 16, H_DIM>
            <<<16 * MT256, 512, 0, stream>>>(xb, wt, cnt, (void*)act);
        transpose_cvt<<<dim3(H_DIM / 64, F_DIM / 64, E_NUM), NT, 0, stream>>>(
            w2, wt, F_DIM, H_DIM);
        gemm8p<false, H_DIM, 4, F_DIM>
            <<<4 * MT256, 512, 0, stream>>>(act, wt, cnt, (void*)out);
    } else if (ws_size >= ACT_B) {
        short* act = (short*)d_ws;
        gemm1_kernel<<<dim3(F_DIM / 128, MT_MAX), NT, 0, stream>>>(x, w1, cnt, act);
        gemm2_kernel<<<dim3(H_DIM / 128, MT_MAX), NT, 0, stream>>>(act, w2, cnt, out);
    }
}